// Round 1
// baseline (71.362 us; speedup 1.0000x reference)
//
#include <hip/hip_runtime.h>

#define SDIM 7
#define NPIX 49            // S*S
#define CCH 512
#define FLAT (CCH * NPIX)  // 25088 floats per batch per tensor
#define THRESH 0.7f
#define EPSN 1e-6f

// One block per batch element b.
// Phase 1: 245 threads (5 c-groups x 49 pixels) compute per-pixel channel
//          reductions (sum b^2, sum m^2, sum b*m) with coalesced reads.
// Phase 2: cos[j], warp grids in LDS.
// Phase 3: 49x49 pair loop -> masked sums; block reduce; atomic accumulate.
__global__ __launch_bounds__(256) void pixpro_main(
    const float* __restrict__ base, const float* __restrict__ moment,
    const float* __restrict__ pb, const float* __restrict__ pm,
    const int* __restrict__ fb, const int* __restrict__ fm,
    float* __restrict__ accum)  // accum[0]=sum contrib, accum[1]=inter count
{
    const int b   = blockIdx.x;
    const int tid = threadIdx.x;

    __shared__ float lds_sqb[5 * NPIX];
    __shared__ float lds_sqm[5 * NPIX];
    __shared__ float lds_dot[5 * NPIX];
    __shared__ float cosj[NPIX];
    __shared__ float gbx[NPIX], gby[NPIX], gmx[NPIX], gmy[NPIX];
    __shared__ float red[4 * 4];

    // ---- Phase 1: channel reductions, coalesced (block reads contiguous
    //      245-float spans each iteration: idx = tid + 245*k) ----
    if (tid < 5 * NPIX) {
        const int j  = tid % NPIX;
        const int c0 = tid / NPIX;
        const float* bp = base   + (size_t)b * FLAT;
        const float* mp = moment + (size_t)b * FLAT;
        float asq = 0.f, msq = 0.f, dot = 0.f;
        for (int c = c0; c < CCH; c += 5) {
            float x = bp[c * NPIX + j];
            float y = mp[c * NPIX + j];
            asq = fmaf(x, x, asq);
            msq = fmaf(y, y, msq);
            dot = fmaf(x, y, dot);
        }
        lds_sqb[tid] = asq;
        lds_sqm[tid] = msq;
        lds_dot[tid] = dot;
    }

    // ---- box params (broadcast reads, cached) ----
    const float xb = pb[b * 4 + 0], yb = pb[b * 4 + 1];
    const float wb = pb[b * 4 + 2], hb = pb[b * 4 + 3];
    const float xm = pm[b * 4 + 0], ym = pm[b * 4 + 1];
    const float wm = pm[b * 4 + 2], hm = pm[b * 4 + 3];
    const bool flb = (fb[b] != 0);
    const bool flm = (fm[b] != 0);

    __syncthreads();

    // ---- Phase 2: cos[j] and warp grids ----
    if (tid < NPIX) {
        float sqb = 0.f, sqm = 0.f, dt = 0.f;
        for (int g = 0; g < 5; ++g) {
            sqb += lds_sqb[g * NPIX + tid];
            sqm += lds_sqm[g * NPIX + tid];
            dt  += lds_dot[g * NPIX + tid];
        }
        float nb = fmaxf(sqrtf(sqb), EPSN);
        float nm = fmaxf(sqrtf(sqm), EPSN);
        cosj[tid] = dt / (nb * nm);

        // grid: n = i*7 + jj ; g[i][jj] = (gx[i], gy[flip ? 6-jj : jj])
        const int i  = tid / SDIM;
        const int jj = tid % SDIM;
        const float ti = (float)i * (1.0f / 6.0f);
        const int jb = flb ? (6 - jj) : jj;
        const int jm = flm ? (6 - jj) : jj;
        gbx[tid] = xb + wb * ti;
        gby[tid] = yb + hb * ((float)jb * (1.0f / 6.0f));
        gmx[tid] = xm + wm * ti;
        gmy[tid] = ym + hm * ((float)jm * (1.0f / 6.0f));
    }
    __syncthreads();

    // ---- Phase 3: 49x49 pairs ----
    // A_b[i][j] = dist(gb[i],gm[j]) <  0.7*diag_b  -> s_b += cos[j]
    // A_m contribution (after swapaxes algebra):
    //   dist(gb[i],gm[j]) < 0.7*diag_m            -> s_m += cos[i]
    const float thrb2 = THRESH * THRESH * (wb * wb + hb * hb);
    const float thrm2 = THRESH * THRESH * (wm * wm + hm * hm);
    float sb = 0.f, sm = 0.f;
    int nnzb = 0, nnzm = 0;
    for (int p = tid; p < NPIX * NPIX; p += 256) {
        const int i = p / NPIX;
        const int j = p - i * NPIX;
        const float dx = gbx[i] - gmx[j];
        const float dy = gby[i] - gmy[j];
        const float d2 = dx * dx + dy * dy;
        if (d2 < thrb2) { ++nnzb; sb += cosj[j]; }
        if (d2 < thrm2) { ++nnzm; sm += cosj[i]; }
    }

    // wave (64-lane) shuffle reduction, then cross-wave via LDS
    for (int off = 32; off; off >>= 1) {
        sb   += __shfl_down(sb, off);
        sm   += __shfl_down(sm, off);
        nnzb += __shfl_down(nnzb, off);
        nnzm += __shfl_down(nnzm, off);
    }
    const int wid = tid >> 6;
    if ((tid & 63) == 0) {
        red[wid * 4 + 0] = sb;
        red[wid * 4 + 1] = sm;
        red[wid * 4 + 2] = (float)nnzb;
        red[wid * 4 + 3] = (float)nnzm;
    }
    __syncthreads();

    if (tid == 0) {
        float SB = 0.f, SM = 0.f, NB = 0.f, NM = 0.f;
        for (int w = 0; w < 4; ++w) {
            SB += red[w * 4 + 0];
            SM += red[w * 4 + 1];
            NB += red[w * 4 + 2];
            NM += red[w * 4 + 3];
        }
        const float lossb = (NB > 0.f) ? SB / NB : 0.f;  // nnz>=1 when >0
        const float lossm = (NM > 0.f) ? SM / NM : 0.f;
        const float cx1 = xb + 0.5f * wb, cx2 = xm + 0.5f * wm;
        const float cy1 = yb + 0.5f * hb, cy2 = ym + 0.5f * hm;
        const bool inter = (fabsf(cx1 - cx2) * 2.f < wb + wm) &&
                           (fabsf(cy1 - cy2) * 2.f < hb + hm);
        if (inter) {
            atomicAdd(&accum[0], -(lossb + lossm));
            atomicAdd(&accum[1], 1.0f);
        }
    }
}

__global__ void pixpro_final(const float* __restrict__ accum,
                             float* __restrict__ out)
{
    out[0] = accum[0] / fmaxf(accum[1], 1.0f);
}

extern "C" void kernel_launch(void* const* d_in, const int* in_sizes, int n_in,
                              void* d_out, int out_size, void* d_ws, size_t ws_size,
                              hipStream_t stream)
{
    const float* base   = (const float*)d_in[0];
    const float* moment = (const float*)d_in[1];
    const float* pbase  = (const float*)d_in[2];
    const float* pmom   = (const float*)d_in[3];
    const int*   fbase  = (const int*)d_in[4];
    const int*   fmom   = (const int*)d_in[5];
    float* out   = (float*)d_out;
    float* accum = (float*)d_ws;  // 2 floats

    const int B = in_sizes[2] / 4;  // p_base is (B,4)

    hipMemsetAsync(accum, 0, 2 * sizeof(float), stream);
    pixpro_main<<<B, 256, 0, stream>>>(base, moment, pbase, pmom, fbase, fmom, accum);
    pixpro_final<<<1, 1, 0, stream>>>(accum, out);
}